// Round 12
// baseline (68.282 us; speedup 1.0000x reference)
//
#include <hip/hip_runtime.h>
#include <stdint.h>

#define SEQ 2048
#define BATCH 4
#define EMB 512
#define MTOT (BATCH * SEQ)   // 8192 rows
#define WIN 16
#define WINDOW 33            // 2*WIN+1

typedef uint32_t u32;
typedef unsigned short u16;
typedef __attribute__((ext_vector_type(8))) __bf16 bf16x8;
typedef __attribute__((ext_vector_type(4))) float f32x4;
typedef __attribute__((ext_vector_type(4))) u16 u16x4;
typedef __attribute__((ext_vector_type(8))) u16 u16x8;

__device__ __forceinline__ u16 f2bf(float f) {  // RNE f32->bf16
  u32 u = __builtin_bit_cast(u32, f);
  u = (u + 0x7fffu + ((u >> 16) & 1u)) >> 16;
  return (u16)u;
}
__device__ __forceinline__ float bf2f(u16 v) {
  return __builtin_bit_cast(float, (u32)v << 16);
}
__device__ __forceinline__ void gload16(void* lds, const void* g) {
  __builtin_amdgcn_global_load_lds((const __attribute__((address_space(1))) u32*)g,
                                   (__attribute__((address_space(3))) u32*)lds, 16, 0, 0);
}
// Explicit drain of LDS-DMA (vm) + ds ops (lgkm) before a publishing barrier.
// R5/R6 lesson: never rely on the compiler emitting this for DMA-staged LDS.
__device__ __forceinline__ void drain_stage() {
  asm volatile("s_waitcnt vmcnt(0) lgkmcnt(0)" ::: "memory");
}

// ============ launch 1: prep5 — all casts + small reductions ============
// [0,512):    x -> xb (bf16), grid-strided
// [512,768):  Wq -> WqT (transpose-cast) | [768,1024): Wk -> WkT (transpose-cast)
// [1024,1280): Wo -> Wob (cast)          | [1280,1536): Wv -> WvT (transpose-cast)
// [1536,1544): cvec[i] = sum_d Wq[d][i]*bk[d] + Wk[d][i]*bq[d]
// [1544,1552): bc[i] = Wo[i,:].bv + bo[i]
// [1552]:      econst = bq.bk
__global__ void __launch_bounds__(256) prep5(
    const float* __restrict__ x, const float* __restrict__ Wq, const float* __restrict__ Wk,
    const float* __restrict__ Wv, const float* __restrict__ Wo,
    const float* __restrict__ bq, const float* __restrict__ bk,
    const float* __restrict__ bv, const float* __restrict__ bo,
    u16* __restrict__ xb, u16* __restrict__ WqT, u16* __restrict__ WkT,
    u16* __restrict__ Wob, u16* __restrict__ WvT,
    float* __restrict__ cvec, float* __restrict__ bc, float* __restrict__ econst) {
  __shared__ float sm[32][33];
  int b = blockIdx.x, t = threadIdx.x;
  if (b < 512) {                          // ---- x cast (grid-strided float4)
    for (u32 i = b * 256 + t; i < (u32)(MTOT * EMB / 4); i += 512 * 256) {
      float4 v = reinterpret_cast<const float4*>(x)[i];
      u16x4 o; o.x = f2bf(v.x); o.y = f2bf(v.y); o.z = f2bf(v.z); o.w = f2bf(v.w);
      reinterpret_cast<u16x4*>(xb)[i] = o;
    }
  } else if (b < 1280 && !(b >= 1024 && b < 1280)) {  // ---- WqT / WkT transpose-casts
    bool isQ = b < 768;
    int tb = (b - 512) & 255;
    const float* S = isQ ? Wq : Wk;
    u16* D = isQ ? WqT : WkT;
    int ti = tb >> 4, tj = tb & 15;       // ti: d-tile (rows), tj: col-tile
    int lr = t >> 5, lc = t & 31;
#pragma unroll
    for (int rr = 0; rr < 32; rr += 8)
      sm[rr + lr][lc] = S[(size_t)(ti * 32 + rr + lr) * EMB + tj * 32 + lc];
    __syncthreads();
    int jr = t >> 3, dc = (t & 7) * 4;
    u16x4 o;
#pragma unroll
    for (int c = 0; c < 4; ++c) o[c] = f2bf(sm[dc + c][jr]);
    *reinterpret_cast<u16x4*>(D + (size_t)(tj * 32 + jr) * EMB + ti * 32 + dc) = o;
  } else if (b < 1280) {                  // ---- Wo cast (b in [1024,1280))
    int cb = b - 1024;
    int i = (cb * 256 + t) * 4;
    float4 v = *reinterpret_cast<const float4*>(Wo + i);
    u16x4 o; o.x = f2bf(v.x); o.y = f2bf(v.y); o.z = f2bf(v.z); o.w = f2bf(v.w);
    *reinterpret_cast<u16x4*>(Wob + i) = o;
  } else if (b < 1536) {                  // ---- WvT transpose-cast
    int tb = b - 1280;
    int ti = tb >> 4, tj = tb & 15;
    int lr = t >> 5, lc = t & 31;
#pragma unroll
    for (int rr = 0; rr < 32; rr += 8)
      sm[rr + lr][lc] = Wv[(size_t)(ti * 32 + rr + lr) * EMB + tj * 32 + lc];
    __syncthreads();
    int jr = t >> 3, dc = (t & 7) * 4;
    u16x4 o;
#pragma unroll
    for (int c = 0; c < 4; ++c) o[c] = f2bf(sm[dc + c][jr]);
    *reinterpret_cast<u16x4*>(WvT + (size_t)(tj * 32 + jr) * EMB + ti * 32 + dc) = o;
  } else if (b < 1544) {                  // ---- cvec
    float* sh = &sm[0][0];
    int cb = b - 1536;
    int ii = t >> 2, di = t & 3;
    int i = cb * 64 + ii;
    float s = 0.f;
    for (int d = di * 128; d < di * 128 + 128; ++d)
      s += Wq[(size_t)d * EMB + i] * bk[d] + Wk[(size_t)d * EMB + i] * bq[d];
    sh[t] = s;
    __syncthreads();
    if (di == 0) cvec[i] = sh[t] + sh[t + 1] + sh[t + 2] + sh[t + 3];
  } else if (b < 1552) {                  // ---- bc
    float* sh = &sm[0][0];
    int cb = b - 1544;
    int ii = t >> 2, di = t & 3;
    int i = cb * 64 + ii;
    float s = 0.f;
    for (int d = di * 128; d < di * 128 + 128; ++d)
      s += Wo[(size_t)i * EMB + d] * bv[d];
    sh[t] = s;
    __syncthreads();
    if (di == 0) bc[i] = sh[t] + sh[t + 1] + sh[t + 2] + sh[t + 3] + bo[i];
  } else {                                // ---- econst = bq.bk
    float* sh = &sm[0][0];
    float s = bq[t] * bk[t] + bq[t + 256] * bk[t + 256];
    sh[t] = s;
    __syncthreads();
    for (int st = 128; st > 0; st >>= 1) {
      if (t < st) sh[t] += sh[t + st];
      __syncthreads();
    }
    if (t == 0) *econst = sh[0];
  }
}

// ---- 64x64 BT-tile MFMA GEMM body (proven as R10/R11 Wc blocks): C = A @ B^T, bf16 out ----
__device__ __forceinline__ void bt_tile64(
    const u16* __restrict__ Arows, const u16* __restrict__ Brows, u16* __restrict__ C,
    int i0, int j0, int t, char* smem) {
  u16* AL = (u16*)smem;                // 64x32 = 4 KB
  u16* BL = (u16*)(smem + 4096);       // 64x32 = 4 KB
  int wave = t >> 6, lane = t & 63;
  int wr = wave >> 1, wc = wave & 1;
  int fr = lane & 15, fq = lane >> 4;
  f32x4 acc[2][2] = {};
  for (int kt = 0; kt < 16; ++kt) {
    __syncthreads();
    int kb = kt * 32;
    int row = t >> 2, col8 = (t & 3) * 8;
    gload16(AL + (size_t)t * 8, Arows + (size_t)(i0 + row) * EMB + kb + col8);
    gload16(BL + (size_t)t * 8, Brows + (size_t)(j0 + row) * EMB + kb + col8);
    drain_stage();
    __syncthreads();
    bf16x8 af[2], bfv[2];
#pragma unroll
    for (int m = 0; m < 2; ++m)
      af[m] = *reinterpret_cast<const bf16x8*>(&AL[(wr * 32 + m * 16 + fr) * 32 + fq * 8]);
#pragma unroll
    for (int n = 0; n < 2; ++n)
      bfv[n] = *reinterpret_cast<const bf16x8*>(&BL[(wc * 32 + n * 16 + fr) * 32 + fq * 8]);
#pragma unroll
    for (int m = 0; m < 2; ++m)
#pragma unroll
      for (int n = 0; n < 2; ++n)
        acc[m][n] = __builtin_amdgcn_mfma_f32_16x16x32_bf16(af[m], bfv[n], acc[m][n], 0, 0, 0);
  }
#pragma unroll
  for (int m = 0; m < 2; ++m) {
    int wave2 = t >> 6;
    int wr2 = wave2 >> 1, wc2 = wave2 & 1;
    int fr2 = (t & 63) & 15, fq2 = (t & 63) >> 4;
#pragma unroll
    for (int n = 0; n < 2; ++n)
#pragma unroll
      for (int r = 0; r < 4; ++r)
        C[(size_t)(i0 + wr2 * 32 + m * 16 + fq2 * 4 + r) * EMB + j0 + wc2 * 32 + n * 16 + fr2] =
            f2bf(acc[m][n][r]);
  }
}

// ============ launch 2: gemm_atm — Atm[n][k] = sum_d Wk[d][n]*Wq[d][k] = WkT @ WqT^T ========
__global__ void __launch_bounds__(256) gemm_atm(
    const u16* __restrict__ WkT, const u16* __restrict__ WqT, u16* __restrict__ Atm) {
  __shared__ __align__(16) char smem[8192];
  int b = blockIdx.x;                    // 64 blocks
  bt_tile64(WkT, WqT, Atm, (b >> 3) * 64, (b & 7) * 64, threadIdx.x, smem);
}

// ============ launch 3: gemm_e (b<512) || Wc = Wo@Wv (b>=512) ============
// gemm_e: T = xb @ Atm^T (64x128 tiles); e_part[slot][m] = sum_cols (T+cvec)*x.
__global__ void __launch_bounds__(256) gemm_ewc(
    const u16* __restrict__ xb, const u16* __restrict__ Atm,
    const float* __restrict__ x, const float* __restrict__ cvec,
    float* __restrict__ e_part,
    const u16* __restrict__ Wob, const u16* __restrict__ WvT, u16* __restrict__ Wcb) {
  __shared__ __align__(16) char smem[12288];
  int b = blockIdx.x;
  int t = threadIdx.x;
  if (b >= 512) {                        // ---- Wc tile (proven pattern)
    bt_tile64(Wob, WvT, Wcb, ((b - 512) >> 3) * 64, ((b - 512) & 7) * 64, t, smem);
    return;
  }
  u16* At2 = (u16*)smem;                 // 64x32 = 4 KB
  u16* Bt2 = (u16*)(smem + 4096);        // 128x32 = 8 KB
  int wg = ((b & 7) << 6) + (b >> 3);    // XCD-chunked swizzle
  int bx = wg >> 2, by = wg & 3;
  int wave = t >> 6, lane = t & 63;
  int wr = wave >> 1, wc = wave & 1;
  int fr = lane & 15, fq = lane >> 4;
  int m0 = bx * 64, n0 = by * 128;
  f32x4 acc[2][4] = {};
  for (int kt = 0; kt < EMB / 32; ++kt) {
    __syncthreads();
    int kb = kt * 32;
    {
      int row = t >> 2, col = (t & 3) * 8;
      gload16(At2 + (size_t)t * 8, xb + (size_t)(m0 + row) * EMB + kb + col);
    }
#pragma unroll
    for (int it = 0; it < 2; ++it) {
      int chunk = t + it * 256;
      int row = chunk >> 2, col = (chunk & 3) * 8;
      gload16(Bt2 + (size_t)(wave * 64 + it * 256) * 8, Atm + (size_t)(n0 + row) * EMB + kb + col);
    }
    drain_stage();
    __syncthreads();
    bf16x8 af[2], bfv[4];
#pragma unroll
    for (int m = 0; m < 2; ++m)
      af[m] = *reinterpret_cast<const bf16x8*>(&At2[(wr * 32 + m * 16 + fr) * 32 + fq * 8]);
#pragma unroll
    for (int n = 0; n < 4; ++n)
      bfv[n] = *reinterpret_cast<const bf16x8*>(&Bt2[(wc * 64 + n * 16 + fr) * 32 + fq * 8]);
#pragma unroll
    for (int m = 0; m < 2; ++m)
#pragma unroll
      for (int n = 0; n < 4; ++n)
        acc[m][n] = __builtin_amdgcn_mfma_f32_16x16x32_bf16(af[m], bfv[n], acc[m][n], 0, 0, 0);
  }
  // rowdot epilogue (proven R9): p = sum_n (T + cvec)*x, reduce over fr via shfl
  float cv[4];
#pragma unroll
  for (int n = 0; n < 4; ++n) cv[n] = cvec[n0 + wc * 64 + n * 16 + fr];
  int slot = by * 2 + wc;
#pragma unroll
  for (int m = 0; m < 2; ++m) {
#pragma unroll
    for (int r = 0; r < 4; ++r) {
      int row = m0 + wr * 32 + m * 16 + fq * 4 + r;
      float p = 0.f;
#pragma unroll
      for (int n = 0; n < 4; ++n) {
        int col = n0 + wc * 64 + n * 16 + fr;
        p += (acc[m][n][r] + cv[n]) * x[(size_t)row * EMB + col];
      }
      p += __shfl_xor(p, 1);
      p += __shfl_xor(p, 2);
      p += __shfl_xor(p, 4);
      p += __shfl_xor(p, 8);
      if (fr == 0) e_part[(size_t)slot * MTOT + row] = p;
    }
  }
}

// ============ launch 4: window softmax + weighted x-sum -> y (bf16) ============
__global__ void __launch_bounds__(256) window4(
    const u16* __restrict__ xb, const float* __restrict__ e_part,
    const float* __restrict__ econst_p, u16* __restrict__ y) {
  __shared__ u16 Xt[48 * EMB];      // 49152 B
  __shared__ float eloc[48];
  __shared__ float w[16][WINDOW];
  int b = blockIdx.x;                    // 512 blocks
  int swz = ((b & 7) << 6) + (b >> 3);   // XCD-chunked
  int bb = swz >> 7;
  int s0 = (swz & 127) * 16;
  int t = threadIdx.x;
  u16x8 stg[12];
#pragma unroll
  for (int i = 0; i < 12; ++i) {
    int chunk = t + i * 256;
    int row = chunk >> 6;
    int c8 = (chunk & 63) * 8;
    int n = s0 + row - WIN;
    if (n >= 0 && n < SEQ)
      stg[i] = *reinterpret_cast<const u16x8*>(xb + (size_t)(bb * SEQ + n) * EMB + c8);
    else
      stg[i] = (u16x8){0, 0, 0, 0, 0, 0, 0, 0};
  }
#pragma unroll
  for (int i = 0; i < 12; ++i) {
    int chunk = t + i * 256;
    int row = chunk >> 6;
    int c8 = (chunk & 63) * 8;
    *reinterpret_cast<u16x8*>(&Xt[(size_t)row * EMB + c8]) = stg[i];
  }
  const float scale = 0.044194173824159216f;  // 1/sqrt(512)
  float ec = *econst_p;
  if (t < 48) {
    int n = s0 + t - WIN;
    float raw = 0.f;
    if (n >= 0 && n < SEQ) {
      size_t idx = (size_t)bb * SEQ + n;
#pragma unroll
      for (int p = 0; p < 8; ++p) raw += e_part[(size_t)p * MTOT + idx];
    }
    eloc[t] = scale * (raw + ec);        // pad: raw==0 -> scale*bq.bk, exact
  }
  __syncthreads();
  if (t < 16) {
    float ev[WINDOW];
    float mx = -1e30f;
#pragma unroll
    for (int j = 0; j < WINDOW; ++j) { ev[j] = eloc[t + j]; mx = fmaxf(mx, ev[j]); }
    float sum = 0.f;
#pragma unroll
    for (int j = 0; j < WINDOW; ++j) { float ex = __expf(ev[j] - mx); ev[j] = ex; sum += ex; }
    float inv = 1.f / sum;
#pragma unroll
    for (int j = 0; j < WINDOW; ++j) w[t][j] = ev[j] * inv;
  }
  __syncthreads();
  int cg = t & 63;
  int slg = t >> 6;
  int d0 = cg * 8;
  float oacc[4][8] = {};
  for (int ri = 0; ri < 36; ++ri) {
    int r = slg * 4 + ri;
    u16x8 v = *reinterpret_cast<const u16x8*>(&Xt[(size_t)r * EMB + d0]);
    float vf[8];
#pragma unroll
    for (int c = 0; c < 8; ++c) vf[c] = bf2f(v[c]);
#pragma unroll
    for (int q = 0; q < 4; ++q) {
      int j = ri - q;
      if (j >= 0 && j < WINDOW) {
        float wt = w[slg * 4 + q][j];
#pragma unroll
        for (int c = 0; c < 8; ++c) oacc[q][c] += wt * vf[c];
      }
    }
  }
#pragma unroll
  for (int q = 0; q < 4; ++q) {
    u16x8 o;
#pragma unroll
    for (int c = 0; c < 8; ++c) o[c] = f2bf(oacc[q][c]);
    *reinterpret_cast<u16x8*>(&y[(size_t)(bb * SEQ + s0 + slg * 4 + q) * EMB + d0]) = o;
  }
}

// ============ launch 5: out = y @ Wc^T + bc (fp32); both operands via DMA ============
__global__ void __launch_bounds__(256) gemm_o(
    const u16* __restrict__ y, const u16* __restrict__ Wcb,
    const float* __restrict__ bc, float* __restrict__ out) {
  __shared__ u16 At2[64 * 32];    // 4 KB
  __shared__ u16 Bt2[128 * 32];   // 8 KB
  int b = blockIdx.x;                    // 512 blocks
  int wg = ((b & 7) << 6) + (b >> 3);    // XCD-chunked swizzle
  int bx = wg >> 2, by = wg & 3;
  int t = threadIdx.x;
  int wave = t >> 6, lane = t & 63;
  int wr = wave >> 1, wc = wave & 1;
  int fr = lane & 15, fq = lane >> 4;
  int m0 = bx * 64, n0 = by * 128;
  f32x4 acc[2][4] = {};
  for (int kt = 0; kt < EMB / 32; ++kt) {
    __syncthreads();
    int kb = kt * 32;
    {
      int row = t >> 2, col = (t & 3) * 8;
      gload16(At2 + (size_t)t * 8, y + (size_t)(m0 + row) * EMB + kb + col);
    }
#pragma unroll
    for (int it = 0; it < 2; ++it) {
      int chunk = t + it * 256;
      int row = chunk >> 2, col = (chunk & 3) * 8;
      gload16(Bt2 + (size_t)(wave * 64 + it * 256) * 8, Wcb + (size_t)(n0 + row) * EMB + kb + col);
    }
    drain_stage();
    __syncthreads();
    bf16x8 af[2], bfv[4];
#pragma unroll
    for (int m = 0; m < 2; ++m)
      af[m] = *reinterpret_cast<const bf16x8*>(&At2[(wr * 32 + m * 16 + fr) * 32 + fq * 8]);
#pragma unroll
    for (int n = 0; n < 4; ++n)
      bfv[n] = *reinterpret_cast<const bf16x8*>(&Bt2[(wc * 64 + n * 16 + fr) * 32 + fq * 8]);
#pragma unroll
    for (int m = 0; m < 2; ++m)
#pragma unroll
      for (int n = 0; n < 4; ++n)
        acc[m][n] = __builtin_amdgcn_mfma_f32_16x16x32_bf16(af[m], bfv[n], acc[m][n], 0, 0, 0);
  }
  float bcv[4];
#pragma unroll
  for (int n = 0; n < 4; ++n) bcv[n] = bc[n0 + wc * 64 + n * 16 + fr];
#pragma unroll
  for (int m = 0; m < 2; ++m)
#pragma unroll
    for (int n = 0; n < 4; ++n) {
      int col = n0 + wc * 64 + n * 16 + fr;
#pragma unroll
      for (int r = 0; r < 4; ++r) {
        int row = m0 + wr * 32 + m * 16 + fq * 4 + r;
        out[(size_t)row * EMB + col] = acc[m][n][r] + bcv[n];
      }
    }
}

extern "C" void kernel_launch(void* const* d_in, const int* in_sizes, int n_in,
                              void* d_out, int out_size, void* d_ws, size_t ws_size,
                              hipStream_t stream) {
  const float* x  = (const float*)d_in[0];
  const float* Wq = (const float*)d_in[1];
  const float* bq = (const float*)d_in[2];
  const float* Wk = (const float*)d_in[3];
  const float* bk = (const float*)d_in[4];
  const float* Wv = (const float*)d_in[5];
  const float* bv = (const float*)d_in[6];
  const float* Wo = (const float*)d_in[7];
  const float* bo = (const float*)d_in[8];
  float* out = (float*)d_out;

  char* ws = (char*)d_ws;
  u16* xb       = (u16*)(ws);                                    // 8 MB
  u16* y        = (u16*)(ws + (8u << 20));                       // 8 MB
  u16* WqT      = (u16*)(ws + (16u << 20));                      // 512 KB
  u16* WkT      = (u16*)(ws + (16u << 20) + (512u << 10));       // 512 KB
  u16* Wob      = (u16*)(ws + (16u << 20) + (1024u << 10));      // 512 KB
  u16* WvT      = (u16*)(ws + (16u << 20) + (1536u << 10));      // 512 KB
  u16* Atm      = (u16*)(ws + (16u << 20) + (2048u << 10));      // 512 KB
  u16* Wcb      = (u16*)(ws + (16u << 20) + (2560u << 10));      // 512 KB
  float* e_part = (float*)(ws + (16u << 20) + (3072u << 10));    // 256 KB (8 slots)
  float* cvec   = (float*)(ws + (16u << 20) + (3328u << 10));    // 2 KB
  float* bc     = (float*)(ws + (16u << 20) + (3330u << 10));    // 2 KB
  float* econst = (float*)(ws + (16u << 20) + (3332u << 10));    // 4 B

  // 1) all casts + cvec/bc/econst
  prep5<<<1553, 256, 0, stream>>>(x, Wq, Wk, Wv, Wo, bq, bk, bv, bo,
                                  xb, WqT, WkT, Wob, WvT, cvec, bc, econst);
  // 2) Atm = WkT @ WqT^T (MFMA, 64 blocks)
  gemm_atm<<<64, 256, 0, stream>>>(WkT, WqT, Atm);
  // 3) e partials (T = xb@Atm^T + rowdot vs fp32 x)  ||  Wc = Wo@Wv
  gemm_ewc<<<576, 256, 0, stream>>>(xb, Atm, x, cvec, e_part, Wob, WvT, Wcb);
  // 4) window softmax + weighted x-sum -> y
  window4<<<512, 256, 0, stream>>>(xb, e_part, econst, y);
  // 5) out = y @ Wc^T + bc
  gemm_o<<<512, 256, 0, stream>>>(y, Wcb, bc, out);
}

// Round 13
// 66.490 us; speedup vs baseline: 1.0269x; 1.0269x over previous
//
#include <hip/hip_runtime.h>
#include <stdint.h>

#define SEQ 2048
#define BATCH 4
#define EMB 512
#define MTOT (BATCH * SEQ)   // 8192 rows
#define WIN 16
#define WINDOW 33            // 2*WIN+1

typedef uint32_t u32;
typedef unsigned short u16;
typedef __attribute__((ext_vector_type(8))) __bf16 bf16x8;
typedef __attribute__((ext_vector_type(4))) float f32x4;
typedef __attribute__((ext_vector_type(4))) u16 u16x4;
typedef __attribute__((ext_vector_type(8))) u16 u16x8;

__device__ __forceinline__ u16 f2bf(float f) {  // RNE f32->bf16
  u32 u = __builtin_bit_cast(u32, f);
  u = (u + 0x7fffu + ((u >> 16) & 1u)) >> 16;
  return (u16)u;
}
__device__ __forceinline__ float bf2f(u16 v) {
  return __builtin_bit_cast(float, (u32)v << 16);
}
__device__ __forceinline__ void gload16(void* lds, const void* g) {
  __builtin_amdgcn_global_load_lds((const __attribute__((address_space(1))) u32*)g,
                                   (__attribute__((address_space(3))) u32*)lds, 16, 0, 0);
}
// Explicit drain of LDS-DMA (vm) + ds ops (lgkm) before a publishing barrier.
// R5/R6 lesson: never rely on the compiler emitting this for DMA-staged LDS.
__device__ __forceinline__ void drain_stage() {
  asm volatile("s_waitcnt vmcnt(0) lgkmcnt(0)" ::: "memory");
}

// ============ launch 1: prep6 ============
// [0,512):   x -> xb (bf16), grid-strided
// [512,576): Atm[n][k] = sum_d Wk[d][n]*Wq[d][k]  (64x64 MFMA tiles, fp32 transpose-staged)
// [576,640): Wc[i][j]  = sum_d Wo[i][d]*Wv[d][j]  (64x64 MFMA tiles)
// [640,648): cvec | [648,656): bc | [656]: econst
__global__ void __launch_bounds__(256) prep6(
    const float* __restrict__ x, const float* __restrict__ Wq, const float* __restrict__ Wk,
    const float* __restrict__ Wv, const float* __restrict__ Wo,
    const float* __restrict__ bq, const float* __restrict__ bk,
    const float* __restrict__ bv, const float* __restrict__ bo,
    u16* __restrict__ xb, u16* __restrict__ Atm, u16* __restrict__ Wcb,
    float* __restrict__ cvec, float* __restrict__ bc, float* __restrict__ econst) {
  __shared__ __align__(16) char smem[8192];   // 2 x 64x32 bf16 tiles / reduction scratch
  int b = blockIdx.x, t = threadIdx.x;
  if (b < 512) {                          // ---- x cast (grid-strided float4)
    for (u32 i = b * 256 + t; i < (u32)(MTOT * EMB / 4); i += 512 * 256) {
      float4 v = reinterpret_cast<const float4*>(x)[i];
      u16x4 o; o.x = f2bf(v.x); o.y = f2bf(v.y); o.z = f2bf(v.z); o.w = f2bf(v.w);
      reinterpret_cast<u16x4*>(xb)[i] = o;
    }
  } else if (b < 640) {                   // ---- atm (b<576) / wc (b>=576) 64x64 MFMA tile
    bool isAtm = b < 576;
    int tb = isAtm ? (b - 512) : (b - 576);
    int i0 = (tb >> 3) * 64, j0 = (tb & 7) * 64;
    u16* AL = (u16*)smem;                // [64][32] bf16
    u16* BL = (u16*)(smem + 4096);
    int wave = t >> 6, lane = t & 63;
    int wr = wave >> 1, wc = wave & 1;
    int fr = lane & 15, fq = lane >> 4;
    f32x4 acc[2][2] = {};
    for (int kt = 0; kt < 16; ++kt) {
      __syncthreads();                    // prior frag reads consumed
      int kb = kt * 32;
      if (isAtm) {
        // A[i][dd] = Wk[kb+dd][i0+i]  (transpose-stage); B[j][dd] = Wq[kb+dd][j0+j]
#pragma unroll
        for (int p = 0; p < 2; ++p) {
          int idx = t + p * 256;
          int dd = idx >> 4, c4 = (idx & 15) * 4;
          float4 FA = *reinterpret_cast<const float4*>(Wk + (size_t)(kb + dd) * EMB + i0 + c4);
          float4 FB = *reinterpret_cast<const float4*>(Wq + (size_t)(kb + dd) * EMB + j0 + c4);
#pragma unroll
          for (int j = 0; j < 4; ++j) {
            AL[(c4 + j) * 32 + dd] = f2bf(((const float*)&FA)[j]);
            BL[(c4 + j) * 32 + dd] = f2bf(((const float*)&FB)[j]);
          }
        }
      } else {
        // A[i][dd] = Wo[i0+i][kb+dd] (direct); B[j][dd] = Wv[kb+dd][j0+j] (transpose)
#pragma unroll
        for (int p = 0; p < 2; ++p) {
          int idx = t + p * 256;
          int row = idx >> 3, c4 = (idx & 7) * 4;       // direct: 64 rows x 8 float4
          float4 FA = *reinterpret_cast<const float4*>(Wo + (size_t)(i0 + row) * EMB + kb + c4);
          u16x4 oa; oa.x = f2bf(FA.x); oa.y = f2bf(FA.y); oa.z = f2bf(FA.z); oa.w = f2bf(FA.w);
          *reinterpret_cast<u16x4*>(&AL[row * 32 + c4]) = oa;
          int dd = idx >> 4, cc4 = (idx & 15) * 4;      // transpose: 32 rows x 16 float4
          float4 FB = *reinterpret_cast<const float4*>(Wv + (size_t)(kb + dd) * EMB + j0 + cc4);
#pragma unroll
          for (int j = 0; j < 4; ++j)
            BL[(cc4 + j) * 32 + dd] = f2bf(((const float*)&FB)[j]);
        }
      }
      drain_stage();                      // ds_writes landed before publish
      __syncthreads();
      bf16x8 af[2], bfv[2];
#pragma unroll
      for (int m = 0; m < 2; ++m)
        af[m] = *reinterpret_cast<const bf16x8*>(&AL[(wr * 32 + m * 16 + fr) * 32 + fq * 8]);
#pragma unroll
      for (int n = 0; n < 2; ++n)
        bfv[n] = *reinterpret_cast<const bf16x8*>(&BL[(wc * 32 + n * 16 + fr) * 32 + fq * 8]);
#pragma unroll
      for (int m = 0; m < 2; ++m)
#pragma unroll
        for (int n = 0; n < 2; ++n)
          acc[m][n] = __builtin_amdgcn_mfma_f32_16x16x32_bf16(af[m], bfv[n], acc[m][n], 0, 0, 0);
    }
    u16* C = isAtm ? Atm : Wcb;
#pragma unroll
    for (int m = 0; m < 2; ++m)
#pragma unroll
      for (int n = 0; n < 2; ++n)
#pragma unroll
        for (int r = 0; r < 4; ++r)
          C[(size_t)(i0 + wr * 32 + m * 16 + fq * 4 + r) * EMB + j0 + wc * 32 + n * 16 + fr] =
              f2bf(acc[m][n][r]);
  } else if (b < 648) {                   // ---- cvec[i] = sum_d Wq[d][i]*bk[d]+Wk[d][i]*bq[d]
    float* sh = (float*)smem;
    int cb = b - 640;
    int ii = t >> 2, di = t & 3;
    int i = cb * 64 + ii;
    float s = 0.f;
    for (int d = di * 128; d < di * 128 + 128; ++d)
      s += Wq[(size_t)d * EMB + i] * bk[d] + Wk[(size_t)d * EMB + i] * bq[d];
    sh[t] = s;
    __syncthreads();
    if (di == 0) cvec[i] = sh[t] + sh[t + 1] + sh[t + 2] + sh[t + 3];
  } else if (b < 656) {                   // ---- bc[i] = Wo[i,:].bv + bo[i]
    float* sh = (float*)smem;
    int cb = b - 648;
    int ii = t >> 2, di = t & 3;
    int i = cb * 64 + ii;
    float s = 0.f;
    for (int d = di * 128; d < di * 128 + 128; ++d)
      s += Wo[(size_t)i * EMB + d] * bv[d];
    sh[t] = s;
    __syncthreads();
    if (di == 0) bc[i] = sh[t] + sh[t + 1] + sh[t + 2] + sh[t + 3] + bo[i];
  } else {                                // ---- econst = bq.bk
    float* sh = (float*)smem;
    float s = bq[t] * bk[t] + bq[t + 256] * bk[t + 256];
    sh[t] = s;
    __syncthreads();
    for (int st = 128; st > 0; st >>= 1) {
      if (t < st) sh[t] += sh[t + st];
      __syncthreads();
    }
    if (t == 0) *econst = sh[0];
  }
}

// ============ launch 2: gemm_e — T = xb @ Atm^T (64x128); e_part = rowdot vs fp32 x ========
__global__ void __launch_bounds__(256) gemm_e(
    const u16* __restrict__ xb, const u16* __restrict__ Atm,
    const float* __restrict__ x, const float* __restrict__ cvec,
    float* __restrict__ e_part) {
  __shared__ u16 At2[64 * 32];    // 4 KB
  __shared__ u16 Bt2[128 * 32];   // 8 KB
  int b = blockIdx.x;                    // 512 blocks
  int wg = ((b & 7) << 6) + (b >> 3);    // XCD-chunked swizzle
  int bx = wg >> 2, by = wg & 3;
  int t = threadIdx.x;
  int wave = t >> 6, lane = t & 63;
  int wr = wave >> 1, wc = wave & 1;
  int fr = lane & 15, fq = lane >> 4;
  int m0 = bx * 64, n0 = by * 128;
  f32x4 acc[2][4] = {};
  for (int kt = 0; kt < EMB / 32; ++kt) {
    __syncthreads();
    int kb = kt * 32;
    {
      int row = t >> 2, col = (t & 3) * 8;
      gload16(At2 + (size_t)t * 8, xb + (size_t)(m0 + row) * EMB + kb + col);
    }
#pragma unroll
    for (int it = 0; it < 2; ++it) {
      int chunk = t + it * 256;
      int row = chunk >> 2, col = (chunk & 3) * 8;
      gload16(Bt2 + (size_t)(wave * 64 + it * 256) * 8, Atm + (size_t)(n0 + row) * EMB + kb + col);
    }
    drain_stage();
    __syncthreads();
    bf16x8 af[2], bfv[4];
#pragma unroll
    for (int m = 0; m < 2; ++m)
      af[m] = *reinterpret_cast<const bf16x8*>(&At2[(wr * 32 + m * 16 + fr) * 32 + fq * 8]);
#pragma unroll
    for (int n = 0; n < 4; ++n)
      bfv[n] = *reinterpret_cast<const bf16x8*>(&Bt2[(wc * 64 + n * 16 + fr) * 32 + fq * 8]);
#pragma unroll
    for (int m = 0; m < 2; ++m)
#pragma unroll
      for (int n = 0; n < 4; ++n)
        acc[m][n] = __builtin_amdgcn_mfma_f32_16x16x32_bf16(af[m], bfv[n], acc[m][n], 0, 0, 0);
  }
  float cv[4];
#pragma unroll
  for (int n = 0; n < 4; ++n) cv[n] = cvec[n0 + wc * 64 + n * 16 + fr];
  int slot = by * 2 + wc;
#pragma unroll
  for (int m = 0; m < 2; ++m) {
#pragma unroll
    for (int r = 0; r < 4; ++r) {
      int row = m0 + wr * 32 + m * 16 + fq * 4 + r;
      float p = 0.f;
#pragma unroll
      for (int n = 0; n < 4; ++n) {
        int col = n0 + wc * 64 + n * 16 + fr;
        p += (acc[m][n][r] + cv[n]) * x[(size_t)row * EMB + col];
      }
      p += __shfl_xor(p, 1);
      p += __shfl_xor(p, 2);
      p += __shfl_xor(p, 4);
      p += __shfl_xor(p, 8);
      if (fr == 0) e_part[(size_t)slot * MTOT + row] = p;
    }
  }
}

// ============ launch 3: window softmax + weighted x-sum -> y (bf16) ============
__global__ void __launch_bounds__(256) window4(
    const u16* __restrict__ xb, const float* __restrict__ e_part,
    const float* __restrict__ econst_p, u16* __restrict__ y) {
  __shared__ u16 Xt[48 * EMB];      // 49152 B
  __shared__ float eloc[48];
  __shared__ float w[16][WINDOW];
  int b = blockIdx.x;                    // 512 blocks
  int swz = ((b & 7) << 6) + (b >> 3);   // XCD-chunked
  int bb = swz >> 7;
  int s0 = (swz & 127) * 16;
  int t = threadIdx.x;
  u16x8 stg[12];
#pragma unroll
  for (int i = 0; i < 12; ++i) {
    int chunk = t + i * 256;
    int row = chunk >> 6;
    int c8 = (chunk & 63) * 8;
    int n = s0 + row - WIN;
    if (n >= 0 && n < SEQ)
      stg[i] = *reinterpret_cast<const u16x8*>(xb + (size_t)(bb * SEQ + n) * EMB + c8);
    else
      stg[i] = (u16x8){0, 0, 0, 0, 0, 0, 0, 0};
  }
#pragma unroll
  for (int i = 0; i < 12; ++i) {
    int chunk = t + i * 256;
    int row = chunk >> 6;
    int c8 = (chunk & 63) * 8;
    *reinterpret_cast<u16x8*>(&Xt[(size_t)row * EMB + c8]) = stg[i];
  }
  const float scale = 0.044194173824159216f;  // 1/sqrt(512)
  float ec = *econst_p;
  if (t < 48) {
    int n = s0 + t - WIN;
    float raw = 0.f;
    if (n >= 0 && n < SEQ) {
      size_t idx = (size_t)bb * SEQ + n;
#pragma unroll
      for (int p = 0; p < 8; ++p) raw += e_part[(size_t)p * MTOT + idx];
    }
    eloc[t] = scale * (raw + ec);        // pad: raw==0 -> scale*bq.bk, exact
  }
  __syncthreads();
  if (t < 16) {
    float ev[WINDOW];
    float mx = -1e30f;
#pragma unroll
    for (int j = 0; j < WINDOW; ++j) { ev[j] = eloc[t + j]; mx = fmaxf(mx, ev[j]); }
    float sum = 0.f;
#pragma unroll
    for (int j = 0; j < WINDOW; ++j) { float ex = __expf(ev[j] - mx); ev[j] = ex; sum += ex; }
    float inv = 1.f / sum;
#pragma unroll
    for (int j = 0; j < WINDOW; ++j) w[t][j] = ev[j] * inv;
  }
  __syncthreads();
  int cg = t & 63;
  int slg = t >> 6;
  int d0 = cg * 8;
  float oacc[4][8] = {};
  for (int ri = 0; ri < 36; ++ri) {
    int r = slg * 4 + ri;
    u16x8 v = *reinterpret_cast<const u16x8*>(&Xt[(size_t)r * EMB + d0]);
    float vf[8];
#pragma unroll
    for (int c = 0; c < 8; ++c) vf[c] = bf2f(v[c]);
#pragma unroll
    for (int q = 0; q < 4; ++q) {
      int j = ri - q;
      if (j >= 0 && j < WINDOW) {
        float wt = w[slg * 4 + q][j];
#pragma unroll
        for (int c = 0; c < 8; ++c) oacc[q][c] += wt * vf[c];
      }
    }
  }
#pragma unroll
  for (int q = 0; q < 4; ++q) {
    u16x8 o;
#pragma unroll
    for (int c = 0; c < 8; ++c) o[c] = f2bf(oacc[q][c]);
    *reinterpret_cast<u16x8*>(&y[(size_t)(bb * SEQ + s0 + slg * 4 + q) * EMB + d0]) = o;
  }
}

// ============ launch 4: out = y @ Wc^T + bc (fp32); both operands via DMA ============
__global__ void __launch_bounds__(256) gemm_o(
    const u16* __restrict__ y, const u16* __restrict__ Wcb,
    const float* __restrict__ bc, float* __restrict__ out) {
  __shared__ u16 At2[64 * 32];    // 4 KB
  __shared__ u16 Bt2[128 * 32];   // 8 KB
  int b = blockIdx.x;                    // 512 blocks
  int wg = ((b & 7) << 6) + (b >> 3);    // XCD-chunked swizzle
  int bx = wg >> 2, by = wg & 3;
  int t = threadIdx.x;
  int wave = t >> 6, lane = t & 63;
  int wr = wave >> 1, wc = wave & 1;
  int fr = lane & 15, fq = lane >> 4;
  int m0 = bx * 64, n0 = by * 128;
  f32x4 acc[2][4] = {};
  for (int kt = 0; kt < EMB / 32; ++kt) {
    __syncthreads();
    int kb = kt * 32;
    {
      int row = t >> 2, col = (t & 3) * 8;
      gload16(At2 + (size_t)t * 8, y + (size_t)(m0 + row) * EMB + kb + col);
    }
#pragma unroll
    for (int it = 0; it < 2; ++it) {
      int chunk = t + it * 256;
      int row = chunk >> 2, col = (chunk & 3) * 8;
      gload16(Bt2 + (size_t)(wave * 64 + it * 256) * 8, Wcb + (size_t)(n0 + row) * EMB + kb + col);
    }
    drain_stage();
    __syncthreads();
    bf16x8 af[2], bfv[4];
#pragma unroll
    for (int m = 0; m < 2; ++m)
      af[m] = *reinterpret_cast<const bf16x8*>(&At2[(wr * 32 + m * 16 + fr) * 32 + fq * 8]);
#pragma unroll
    for (int n = 0; n < 4; ++n)
      bfv[n] = *reinterpret_cast<const bf16x8*>(&Bt2[(wc * 64 + n * 16 + fr) * 32 + fq * 8]);
#pragma unroll
    for (int m = 0; m < 2; ++m)
#pragma unroll
      for (int n = 0; n < 4; ++n)
        acc[m][n] = __builtin_amdgcn_mfma_f32_16x16x32_bf16(af[m], bfv[n], acc[m][n], 0, 0, 0);
  }
  float bcv[4];
#pragma unroll
  for (int n = 0; n < 4; ++n) bcv[n] = bc[n0 + wc * 64 + n * 16 + fr];
#pragma unroll
  for (int m = 0; m < 2; ++m)
#pragma unroll
    for (int n = 0; n < 4; ++n) {
      int col = n0 + wc * 64 + n * 16 + fr;
#pragma unroll
      for (int r = 0; r < 4; ++r) {
        int row = m0 + wr * 32 + m * 16 + fq * 4 + r;
        out[(size_t)row * EMB + col] = acc[m][n][r] + bcv[n];
      }
    }
}

extern "C" void kernel_launch(void* const* d_in, const int* in_sizes, int n_in,
                              void* d_out, int out_size, void* d_ws, size_t ws_size,
                              hipStream_t stream) {
  const float* x  = (const float*)d_in[0];
  const float* Wq = (const float*)d_in[1];
  const float* bq = (const float*)d_in[2];
  const float* Wk = (const float*)d_in[3];
  const float* bk = (const float*)d_in[4];
  const float* Wv = (const float*)d_in[5];
  const float* bv = (const float*)d_in[6];
  const float* Wo = (const float*)d_in[7];
  const float* bo = (const float*)d_in[8];
  float* out = (float*)d_out;

  char* ws = (char*)d_ws;
  u16* xb       = (u16*)(ws);                                    // 8 MB
  u16* y        = (u16*)(ws + (8u << 20));                       // 8 MB
  u16* Atm      = (u16*)(ws + (16u << 20));                      // 512 KB
  u16* Wcb      = (u16*)(ws + (16u << 20) + (512u << 10));       // 512 KB
  float* e_part = (float*)(ws + (16u << 20) + (1024u << 10));    // 256 KB (8 slots)
  float* cvec   = (float*)(ws + (16u << 20) + (1280u << 10));    // 2 KB
  float* bc     = (float*)(ws + (16u << 20) + (1282u << 10));    // 2 KB
  float* econst = (float*)(ws + (16u << 20) + (1284u << 10));    // 4 B

  // 1) x-cast || Atm (MFMA from fp32) || Wc (MFMA from fp32) || cvec/bc/econst
  prep6<<<657, 256, 0, stream>>>(x, Wq, Wk, Wv, Wo, bq, bk, bv, bo,
                                 xb, Atm, Wcb, cvec, bc, econst);
  // 2) e partials (T = xb@Atm^T + rowdot vs fp32 x)
  gemm_e<<<512, 256, 0, stream>>>(xb, Atm, x, cvec, e_part);
  // 3) window softmax + weighted x-sum -> y
  window4<<<512, 256, 0, stream>>>(xb, e_part, econst, y);
  // 4) out = y @ Wc^T + bc
  gemm_o<<<512, 256, 0, stream>>>(y, Wcb, bc, out);
}

// Round 14
// 59.318 us; speedup vs baseline: 1.1511x; 1.1209x over previous
//
#include <hip/hip_runtime.h>
#include <stdint.h>

#define SEQ 2048
#define BATCH 4
#define EMB 512
#define MTOT (BATCH * SEQ)   // 8192 rows
#define WIN 16
#define WINDOW 33            // 2*WIN+1

typedef uint32_t u32;
typedef unsigned short u16;
typedef __attribute__((ext_vector_type(8))) __bf16 bf16x8;
typedef __attribute__((ext_vector_type(4))) float f32x4;
typedef __attribute__((ext_vector_type(4))) u16 u16x4;
typedef __attribute__((ext_vector_type(8))) u16 u16x8;

__device__ __forceinline__ u16 f2bf(float f) {  // RNE f32->bf16
  u32 u = __builtin_bit_cast(u32, f);
  u = (u + 0x7fffu + ((u >> 16) & 1u)) >> 16;
  return (u16)u;
}
__device__ __forceinline__ float bf2f(u16 v) {
  return __builtin_bit_cast(float, (u32)v << 16);
}
__device__ __forceinline__ void gload16(void* lds, const void* g) {
  __builtin_amdgcn_global_load_lds((const __attribute__((address_space(1))) u32*)g,
                                   (__attribute__((address_space(3))) u32*)lds, 16, 0, 0);
}
// Explicit drain of LDS-DMA (vm) + ds ops (lgkm) before a publishing barrier.
// R5/R6 lesson: never rely on the compiler emitting this for DMA-staged LDS.
__device__ __forceinline__ void drain_stage() {
  asm volatile("s_waitcnt vmcnt(0) lgkmcnt(0)" ::: "memory");
}

// ============ launch 1: prep3 — pure memory-bound casts + tiny reductions ============
// [0,1024):    x -> xb (bf16), grid-strided
// [1024,1280): Wq -> Wqb        [1280,1536): Wk -> Wkb        [1536,1792): Wo -> Wob
// [1792,2048): Wv -> WvT (transpose-cast, 32x32 tiles)
// [2048,2056): bc[i] = Wo[i,:].bv + bo[i]
// [2056]:      econst = bq.bk
__global__ void __launch_bounds__(256) prep3(
    const float* __restrict__ x, const float* __restrict__ Wq, const float* __restrict__ Wk,
    const float* __restrict__ Wv, const float* __restrict__ Wo,
    const float* __restrict__ bq, const float* __restrict__ bk,
    const float* __restrict__ bv, const float* __restrict__ bo,
    u16* __restrict__ xb, u16* __restrict__ Wqb, u16* __restrict__ Wkb,
    u16* __restrict__ Wob, u16* __restrict__ WvT,
    float* __restrict__ bc, float* __restrict__ econst) {
  __shared__ float sm[32][33];
  int b = blockIdx.x, t = threadIdx.x;
  if (b < 1024) {                         // ---- x cast (grid-strided float4)
    for (u32 i = b * 256 + t; i < (u32)(MTOT * EMB / 4); i += 1024 * 256) {
      float4 v = reinterpret_cast<const float4*>(x)[i];
      u16x4 o; o.x = f2bf(v.x); o.y = f2bf(v.y); o.z = f2bf(v.z); o.w = f2bf(v.w);
      reinterpret_cast<u16x4*>(xb)[i] = o;
    }
  } else if (b < 1792) {                  // ---- Wq / Wk / Wo casts
    const float* S = (b < 1280) ? Wq : (b < 1536) ? Wk : Wo;
    u16* D = (b < 1280) ? Wqb : (b < 1536) ? Wkb : Wob;
    int cb = (b - 1024) & 255;
    int i = (cb * 256 + t) * 4;
    float4 v = *reinterpret_cast<const float4*>(S + i);
    u16x4 o; o.x = f2bf(v.x); o.y = f2bf(v.y); o.z = f2bf(v.z); o.w = f2bf(v.w);
    *reinterpret_cast<u16x4*>(D + i) = o;
  } else if (b < 2048) {                  // ---- WvT[j][k] = Wv[k][j] (32x32 tile)
    int tb = b - 1792;
    int ti = tb >> 4, tj = tb & 15;       // ti: k-tile, tj: j-tile
    int lr = t >> 5, lc = t & 31;
#pragma unroll
    for (int rr = 0; rr < 32; rr += 8)
      sm[rr + lr][lc] = Wv[(size_t)(ti * 32 + rr + lr) * EMB + tj * 32 + lc];
    __syncthreads();
    int jr = t >> 3, dc = (t & 7) * 4;
    u16x4 o;
#pragma unroll
    for (int c = 0; c < 4; ++c) o[c] = f2bf(sm[dc + c][jr]);
    *reinterpret_cast<u16x4*>(WvT + (size_t)(tj * 32 + jr) * EMB + ti * 32 + dc) = o;
  } else if (b < 2056) {                  // ---- bc
    float* sh = &sm[0][0];
    int cb = b - 2048;
    int ii = t >> 2, di = t & 3;
    int i = cb * 64 + ii;
    float s = 0.f;
    for (int d = di * 128; d < di * 128 + 128; ++d)
      s += Wo[(size_t)i * EMB + d] * bv[d];
    sh[t] = s;
    __syncthreads();
    if (di == 0) bc[i] = sh[t] + sh[t + 1] + sh[t + 2] + sh[t + 3] + bo[i];
  } else {                                // ---- econst = bq.bk
    float* sh = &sm[0][0];
    float s = bq[t] * bk[t] + bq[t + 256] * bk[t + 256];
    sh[t] = s;
    __syncthreads();
    for (int st = 128; st > 0; st >>= 1) {
      if (t < st) sh[t] += sh[t + st];
      __syncthreads();
    }
    if (t == 0) *econst = sh[0];
  }
}

// ============ launch 2: gemm_qk — e_part via direct (Q+bq).(K+bk) dual-acc MFMA ============
// 64-row m-tiles x 128-col n-tiles, BK=64, full K per block (split-K invalid for product).
// slot = by*2+wc (8 slots).
__global__ void __launch_bounds__(256) gemm_qk(
    const u16* __restrict__ xb, const u16* __restrict__ Wqb, const u16* __restrict__ Wkb,
    const float* __restrict__ bq, const float* __restrict__ bk,
    float* __restrict__ e_part) {
  __shared__ u16 XL[64 * 64];     // 8 KB
  __shared__ u16 QL[128 * 64];    // 16 KB
  __shared__ u16 KL[128 * 64];    // 16 KB
  int b = blockIdx.x;                    // 512 blocks
  int wg = ((b & 7) << 6) + (b >> 3);    // XCD-chunked swizzle (512 = 8*64)
  int bx = wg >> 2, by = wg & 3;
  int t = threadIdx.x;
  int wave = t >> 6, lane = t & 63;
  int wr = wave >> 1, wc = wave & 1;
  int fr = lane & 15, fq = lane >> 4;
  int m0 = bx * 64, n0 = by * 128;
  f32x4 accQ[2][4] = {};
  f32x4 accK[2][4] = {};
  for (int kt = 0; kt < 8; ++kt) {
    __syncthreads();
    int kb = kt * 64;
#pragma unroll
    for (int it = 0; it < 2; ++it) {     // X: 64x64
      int chunk = t + it * 256;
      int row = chunk >> 3, col8 = (chunk & 7) * 8;
      gload16(XL + (size_t)(wave * 64 + it * 256) * 8, xb + (size_t)(m0 + row) * EMB + kb + col8);
    }
#pragma unroll
    for (int it = 0; it < 4; ++it) {     // Q-weights: 128x64
      int chunk = t + it * 256;
      int row = chunk >> 3, col8 = (chunk & 7) * 8;
      gload16(QL + (size_t)(wave * 64 + it * 256) * 8, Wqb + (size_t)(n0 + row) * EMB + kb + col8);
    }
#pragma unroll
    for (int it = 0; it < 4; ++it) {     // K-weights: 128x64
      int chunk = t + it * 256;
      int row = chunk >> 3, col8 = (chunk & 7) * 8;
      gload16(KL + (size_t)(wave * 64 + it * 256) * 8, Wkb + (size_t)(n0 + row) * EMB + kb + col8);
    }
    drain_stage();                       // all DMA landed before publish
    __syncthreads();
    bf16x8 af[2][2];
#pragma unroll
    for (int m = 0; m < 2; ++m)
#pragma unroll
      for (int kk = 0; kk < 2; ++kk)
        af[m][kk] = *reinterpret_cast<const bf16x8*>(
            &XL[(wr * 32 + m * 16 + fr) * 64 + kk * 32 + fq * 8]);
#pragma unroll
    for (int kk = 0; kk < 2; ++kk)
#pragma unroll
      for (int n = 0; n < 4; ++n) {
        bf16x8 bq_ = *reinterpret_cast<const bf16x8*>(
            &QL[(wc * 64 + n * 16 + fr) * 64 + kk * 32 + fq * 8]);
#pragma unroll
        for (int m = 0; m < 2; ++m)
          accQ[m][n] = __builtin_amdgcn_mfma_f32_16x16x32_bf16(af[m][kk], bq_, accQ[m][n], 0, 0, 0);
        bf16x8 bk_ = *reinterpret_cast<const bf16x8*>(
            &KL[(wc * 64 + n * 16 + fr) * 64 + kk * 32 + fq * 8]);
#pragma unroll
        for (int m = 0; m < 2; ++m)
          accK[m][n] = __builtin_amdgcn_mfma_f32_16x16x32_bf16(af[m][kk], bk_, accK[m][n], 0, 0, 0);
      }
  }
  float bqv[4], bkv[4];
#pragma unroll
  for (int n = 0; n < 4; ++n) {
    int col = n0 + wc * 64 + n * 16 + fr;
    bqv[n] = bq[col];
    bkv[n] = bk[col];
  }
  int slot = by * 2 + wc;
#pragma unroll
  for (int m = 0; m < 2; ++m) {
#pragma unroll
    for (int r = 0; r < 4; ++r) {
      int row = m0 + wr * 32 + m * 16 + fq * 4 + r;
      float p = 0.f;
#pragma unroll
      for (int n = 0; n < 4; ++n)
        p += (accQ[m][n][r] + bqv[n]) * (accK[m][n][r] + bkv[n]);
      p += __shfl_xor(p, 1);
      p += __shfl_xor(p, 2);
      p += __shfl_xor(p, 4);
      p += __shfl_xor(p, 8);
      if (fr == 0) e_part[(size_t)slot * MTOT + row] = p;
    }
  }
}

// ============ launch 3: window softmax + weighted x-sum -> y  ||  Wc = Wo@Wv (MFMA) ========
// blocks [0,512): window (reads xb, e_part; writes y)
// blocks [512,576): Wc 64x64 tiles (reads Wob, WvT; writes Wcb — consumed only by launch 4)
__global__ void __launch_bounds__(256) window3(
    const u16* __restrict__ xb, const float* __restrict__ e_part,
    const float* __restrict__ econst_p, u16* __restrict__ y,
    const u16* __restrict__ Wob, const u16* __restrict__ WvT, u16* __restrict__ Wcb) {
  __shared__ __align__(16) char smem[51456];
  int b = blockIdx.x;
  int t = threadIdx.x;
  if (b >= 512) {                        // ---- Wc tile: 64x64, BK=32, DMA-staged
    u16* AL = (u16*)smem;                // 64x32 = 4 KB
    u16* BL = (u16*)(smem + 4096);       // 64x32 = 4 KB
    int wcb = b - 512;
    int i0 = (wcb >> 3) * 64, j0 = (wcb & 7) * 64;
    int wave = t >> 6, lane = t & 63;
    int wr = wave >> 1, wc = wave & 1;
    int fr = lane & 15, fq = lane >> 4;
    f32x4 acc[2][2] = {};
    for (int kt = 0; kt < 16; ++kt) {
      __syncthreads();
      int kb = kt * 32;
      int row = t >> 2, col8 = (t & 3) * 8;
      gload16(AL + (size_t)t * 8, Wob + (size_t)(i0 + row) * EMB + kb + col8);
      gload16(BL + (size_t)t * 8, WvT + (size_t)(j0 + row) * EMB + kb + col8);
      drain_stage();
      __syncthreads();
      bf16x8 af[2], bfv[2];
#pragma unroll
      for (int m = 0; m < 2; ++m)
        af[m] = *reinterpret_cast<const bf16x8*>(&AL[(wr * 32 + m * 16 + fr) * 32 + fq * 8]);
#pragma unroll
      for (int n = 0; n < 2; ++n)
        bfv[n] = *reinterpret_cast<const bf16x8*>(&BL[(wc * 32 + n * 16 + fr) * 32 + fq * 8]);
#pragma unroll
      for (int m = 0; m < 2; ++m)
#pragma unroll
        for (int n = 0; n < 2; ++n)
          acc[m][n] = __builtin_amdgcn_mfma_f32_16x16x32_bf16(af[m], bfv[n], acc[m][n], 0, 0, 0);
    }
#pragma unroll
    for (int m = 0; m < 2; ++m)
#pragma unroll
      for (int n = 0; n < 2; ++n)
#pragma unroll
        for (int r = 0; r < 4; ++r)
          Wcb[(size_t)(i0 + wr * 32 + m * 16 + fq * 4 + r) * EMB + j0 + wc * 32 + n * 16 + fr] =
              f2bf(acc[m][n][r]);
    return;
  }
  // ---- window path ----
  u16* Xt = (u16*)smem;                                    // 48 x 512 bf16 = 49152 B
  float* eloc = (float*)(smem + 49152);                    // 48
  float (*w)[WINDOW] = (float (*)[WINDOW])(smem + 49344);  // 16 x 33
  int swz = ((b & 7) << 6) + (b >> 3);   // XCD-chunked
  int bb = swz >> 7;
  int s0 = (swz & 127) * 16;
  // stage 48 x rows (zeros for pads): reg-staged (R6 lesson: no divergent-source DMA)
  u16x8 stg[12];
#pragma unroll
  for (int i = 0; i < 12; ++i) {
    int chunk = t + i * 256;
    int row = chunk >> 6;
    int c8 = (chunk & 63) * 8;
    int n = s0 + row - WIN;
    if (n >= 0 && n < SEQ)
      stg[i] = *reinterpret_cast<const u16x8*>(xb + (size_t)(bb * SEQ + n) * EMB + c8);
    else
      stg[i] = (u16x8){0, 0, 0, 0, 0, 0, 0, 0};
  }
#pragma unroll
  for (int i = 0; i < 12; ++i) {
    int chunk = t + i * 256;
    int row = chunk >> 6;
    int c8 = (chunk & 63) * 8;
    *reinterpret_cast<u16x8*>(&Xt[(size_t)row * EMB + c8]) = stg[i];
  }
  const float scale = 0.044194173824159216f;  // 1/sqrt(512)
  float ec = *econst_p;
  if (t < 48) {
    int n = s0 + t - WIN;
    float raw = 0.f;
    if (n >= 0 && n < SEQ) {
      size_t idx = (size_t)bb * SEQ + n;
#pragma unroll
      for (int p = 0; p < 8; ++p) raw += e_part[(size_t)p * MTOT + idx];
    }
    eloc[t] = scale * (raw + ec);        // pad: raw==0 -> scale*bq.bk, exact
  }
  __syncthreads();
  if (t < 16) {
    float ev[WINDOW];
    float mx = -1e30f;
#pragma unroll
    for (int j = 0; j < WINDOW; ++j) { ev[j] = eloc[t + j]; mx = fmaxf(mx, ev[j]); }
    float sum = 0.f;
#pragma unroll
    for (int j = 0; j < WINDOW; ++j) { float ex = __expf(ev[j] - mx); ev[j] = ex; sum += ex; }
    float inv = 1.f / sum;
#pragma unroll
    for (int j = 0; j < WINDOW; ++j) w[t][j] = ev[j] * inv;
  }
  __syncthreads();
  int cg = t & 63;
  int slg = t >> 6;
  int d0 = cg * 8;
  float oacc[4][8] = {};
  for (int ri = 0; ri < 36; ++ri) {
    int r = slg * 4 + ri;
    u16x8 v = *reinterpret_cast<const u16x8*>(&Xt[(size_t)r * EMB + d0]);
    float vf[8];
#pragma unroll
    for (int c = 0; c < 8; ++c) vf[c] = bf2f(v[c]);
#pragma unroll
    for (int q = 0; q < 4; ++q) {
      int j = ri - q;
      if (j >= 0 && j < WINDOW) {
        float wt = w[slg * 4 + q][j];
#pragma unroll
        for (int c = 0; c < 8; ++c) oacc[q][c] += wt * vf[c];
      }
    }
  }
#pragma unroll
  for (int q = 0; q < 4; ++q) {
    u16x8 o;
#pragma unroll
    for (int c = 0; c < 8; ++c) o[c] = f2bf(oacc[q][c]);
    *reinterpret_cast<u16x8*>(&y[(size_t)(bb * SEQ + s0 + slg * 4 + q) * EMB + d0]) = o;
  }
}

// ============ launch 4: out = y @ Wc^T + bc (fp32); both operands via DMA ============
__global__ void __launch_bounds__(256) gemm_o(
    const u16* __restrict__ y, const u16* __restrict__ Wcb,
    const float* __restrict__ bc, float* __restrict__ out) {
  __shared__ u16 At2[64 * 32];    // 4 KB
  __shared__ u16 Bt2[128 * 32];   // 8 KB
  int b = blockIdx.x;                    // 512 blocks
  int wg = ((b & 7) << 6) + (b >> 3);    // XCD-chunked swizzle
  int bx = wg >> 2, by = wg & 3;
  int t = threadIdx.x;
  int wave = t >> 6, lane = t & 63;
  int wr = wave >> 1, wc = wave & 1;
  int fr = lane & 15, fq = lane >> 4;
  int m0 = bx * 64, n0 = by * 128;
  f32x4 acc[2][4] = {};
  for (int kt = 0; kt < EMB / 32; ++kt) {
    __syncthreads();
    int kb = kt * 32;
    {
      int row = t >> 2, col = (t & 3) * 8;
      gload16(At2 + (size_t)t * 8, y + (size_t)(m0 + row) * EMB + kb + col);
    }
#pragma unroll
    for (int it = 0; it < 2; ++it) {
      int chunk = t + it * 256;
      int row = chunk >> 2, col = (chunk & 3) * 8;
      gload16(Bt2 + (size_t)(wave * 64 + it * 256) * 8, Wcb + (size_t)(n0 + row) * EMB + kb + col);
    }
    drain_stage();
    __syncthreads();
    bf16x8 af[2], bfv[4];
#pragma unroll
    for (int m = 0; m < 2; ++m)
      af[m] = *reinterpret_cast<const bf16x8*>(&At2[(wr * 32 + m * 16 + fr) * 32 + fq * 8]);
#pragma unroll
    for (int n = 0; n < 4; ++n)
      bfv[n] = *reinterpret_cast<const bf16x8*>(&Bt2[(wc * 64 + n * 16 + fr) * 32 + fq * 8]);
#pragma unroll
    for (int m = 0; m < 2; ++m)
#pragma unroll
      for (int n = 0; n < 4; ++n)
        acc[m][n] = __builtin_amdgcn_mfma_f32_16x16x32_bf16(af[m], bfv[n], acc[m][n], 0, 0, 0);
  }
  float bcv[4];
#pragma unroll
  for (int n = 0; n < 4; ++n) bcv[n] = bc[n0 + wc * 64 + n * 16 + fr];
#pragma unroll
  for (int m = 0; m < 2; ++m)
#pragma unroll
    for (int n = 0; n < 4; ++n) {
      int col = n0 + wc * 64 + n * 16 + fr;
#pragma unroll
      for (int r = 0; r < 4; ++r) {
        int row = m0 + wr * 32 + m * 16 + fq * 4 + r;
        out[(size_t)row * EMB + col] = acc[m][n][r] + bcv[n];
      }
    }
}

extern "C" void kernel_launch(void* const* d_in, const int* in_sizes, int n_in,
                              void* d_out, int out_size, void* d_ws, size_t ws_size,
                              hipStream_t stream) {
  const float* x  = (const float*)d_in[0];
  const float* Wq = (const float*)d_in[1];
  const float* bq = (const float*)d_in[2];
  const float* Wk = (const float*)d_in[3];
  const float* bk = (const float*)d_in[4];
  const float* Wv = (const float*)d_in[5];
  const float* bv = (const float*)d_in[6];
  const float* Wo = (const float*)d_in[7];
  const float* bo = (const float*)d_in[8];
  float* out = (float*)d_out;

  char* ws = (char*)d_ws;
  u16* xb       = (u16*)(ws);                                    // 8 MB
  u16* y        = (u16*)(ws + (8u << 20));                       // 8 MB
  u16* Wqb      = (u16*)(ws + (16u << 20));                      // 512 KB
  u16* Wkb      = (u16*)(ws + (16u << 20) + (512u << 10));       // 512 KB
  u16* Wob      = (u16*)(ws + (16u << 20) + (1024u << 10));      // 512 KB
  u16* WvT      = (u16*)(ws + (16u << 20) + (1536u << 10));      // 512 KB
  u16* Wcb      = (u16*)(ws + (16u << 20) + (2048u << 10));      // 512 KB
  float* e_part = (float*)(ws + (16u << 20) + (2560u << 10));    // 256 KB (8 slots)
  float* bc     = (float*)(ws + (16u << 20) + (2816u << 10));    // 2 KB
  float* econst = (float*)(ws + (16u << 20) + (2818u << 10));    // 4 B

  // 1) pure casts + bc + econst
  prep3<<<2057, 256, 0, stream>>>(x, Wq, Wk, Wv, Wo, bq, bk, bv, bo,
                                  xb, Wqb, Wkb, Wob, WvT, bc, econst);
  // 2) e = (Q+bq).(K+bk) via dual-acc MFMA, DMA-staged
  gemm_qk<<<512, 256, 0, stream>>>(xb, Wqb, Wkb, bq, bk, e_part);
  // 3) window softmax + weighted x-sum -> y  ||  Wc = Wo@Wv (MFMA)
  window3<<<576, 256, 0, stream>>>(xb, e_part, econst, y, Wob, WvT, Wcb);
  // 4) out = y @ Wc^T + bc
  gemm_o<<<512, 256, 0, stream>>>(y, Wcb, bc, out);
}